// Round 5
// baseline (79.734 us; speedup 1.0000x reference)
//
#include <hip/hip_runtime.h>
#include <math.h>

// Problem constants (fixed by reference setup_inputs)
#define N_TOT 8192
#define M_TOT 16384
#define EPS_N 1024      // M / N_EMB
#define N_EMB 16

#define LOG2E 1.4426950408889634f
#define LN2   0.6931471805599453f
#define EXP2(x) __builtin_amdgcn_exp2f(x)   // v_exp_f32
#define LOG2F_(x) __builtin_amdgcn_logf(x)  // v_log_f32 (log2)

// K1 tiling: product-grid factorization e_j = m_k + T*u_l  (j = k*1024 + l)
//   t_ij = A_ik + B_il,  P=2^A (8192x16), Q=2^B (8192x1024), S_kl = sum_i P_ik Q_il
// Geometry (proven round 4): LCH=256 (4 l's/lane), IC=128, grid 4x64 = 256
// blocks = 1/CU (co-resident by construction).
#define BLOCK 256
#define IC    128            // i's per block
#define NICH  (N_TOT / IC)   // 64 i-chunks
#define LCH   256            // l's per block
#define NLCH  (EPS_N / LCH)  // 4 l-chunks

// Flag value for poison-safe signaling. Workspace is re-poisoned (256 MiB fill)
// every iteration, destroying stale flags; poison pattern cannot plausibly
// equal this non-byte-repeating constant.
#define MAGIC 0x5F3759DFu

#define WT_STORE_F(p, v) __hip_atomic_store((p), (v), __ATOMIC_RELAXED, __HIP_MEMORY_SCOPE_AGENT)
#define WT_STORE_U(p, v) __hip_atomic_store((p), (v), __ATOMIC_RELAXED, __HIP_MEMORY_SCOPE_AGENT)
#define COH_LOAD_F(p)    __hip_atomic_load((p), __ATOMIC_RELAXED, __HIP_MEMORY_SCOPE_AGENT)
#define COH_LOAD_U(p)    __hip_atomic_load((p), __ATOMIC_RELAXED, __HIP_MEMORY_SCOPE_AGENT)
#define VMCNT0()         asm volatile("s_waitcnt vmcnt(0)" ::: "memory")

// Single dispatch. Phase 1 = round-4 gemm partials (identical math), but part
// is stored WRITE-THROUGH (agent-scope atomic stores, sc0/sc1) so L2 never
// holds dirty intermediate data -> the cross-block fence is cheap (round-1
// lesson: __threadfence with 4 MB dirty L2 = buffer_wbl2 stall x blocks).
// Then: per-column flag barrier -> distributed per-j combine -> once-check
// election for the final scalar. All summation orders fixed => deterministic.
__global__ __launch_bounds__(BLOCK) void fused_kernel(
    const float* __restrict__ z, const float* __restrict__ emb,
    const float* __restrict__ log_sigma, const float* __restrict__ eps,
    const float* __restrict__ temperature,
    float* __restrict__ part,          // [NICH][M_TOT] write-through partials
    float* __restrict__ bsum,          // [256] per-block v-sums (write-through)
    unsigned int* __restrict__ done,   // [256] column-barrier flags
    unsigned int* __restrict__ fin,    // [256] final-election flags
    float* __restrict__ out)
{
    __shared__ float4 rowsP[IC][4];          // 8 KB: P[i][k] as 4 float4s
    __shared__ float2 tbv[IC];               // 1 KB: (T*b0, T*b1) per i
    __shared__ float  red[4][N_EMB * 128];   // 32 KB, reused for two l-halves

    const int t  = threadIdx.x;
    const int c  = blockIdx.x;               // l-column 0..3
    const int ib = blockIdx.y;               // i-chunk 0..63
    const int l0 = c * LCH;
    const int bidx = c * NICH + ib;          // 0..255

    const float ls = log_sigma[0];
    const float T  = temperature[0];
    const float alpha = -0.5f * EXP2(LOG2E * (-2.0f * ls));  // -1/(2 sigma^2)
    const float La  = LOG2E * alpha;
    const float omT = 1.0f - T;

    // ---------------- Phase A: stage P-rows (proven round-4 code)
    {
        const int il = t & (IC - 1);
        const int kh = t >> 7;               // wave-uniform
        const int i  = ib * IC + il;
        const float z0 = z[2 * i], z1 = z[2 * i + 1];
        const float c_  = La * (z0 * z0 + z1 * z1);
        const float b0 = -2.0f * La * z0, b1 = -2.0f * La * z1;
        float4 pa, pb;
#pragma unroll
        for (int kk = 0; kk < 4; ++kk) {
            int k = kh * 8 + kk;
            float m0 = omT * emb[2 * k], m1 = omT * emb[2 * k + 1];
            ((float*)&pa)[kk] = EXP2(c_ + b0 * m0 + b1 * m1);   // P_ik
        }
#pragma unroll
        for (int kk = 0; kk < 4; ++kk) {
            int k = kh * 8 + 4 + kk;
            float m0 = omT * emb[2 * k], m1 = omT * emb[2 * k + 1];
            ((float*)&pb)[kk] = EXP2(c_ + b0 * m0 + b1 * m1);
        }
        rowsP[il][kh * 2]     = pa;
        rowsP[il][kh * 2 + 1] = pb;
        if (kh == 0)
            tbv[il] = make_float2(T * b0, T * b1);
    }

    const int lane = t & 63;
    const int w    = t >> 6;
    const float2* eps2 = (const float2*)eps;
    const float2 ua = eps2[l0 + lane];
    const float2 ub = eps2[l0 + 64 + lane];
    const float2 uc = eps2[l0 + 128 + lane];
    const float2 ud = eps2[l0 + 192 + lane];

    __syncthreads();

    float sa[N_EMB] = {0.0f};
    float sb[N_EMB] = {0.0f};
    float sc_[N_EMB] = {0.0f};
    float sd[N_EMB] = {0.0f};
#pragma unroll 2
    for (int n = 0; n < IC / 4; ++n) {
        const int ir = w * (IC / 4) + n;
        float4 p0 = rowsP[ir][0];
        float4 p1 = rowsP[ir][1];
        float4 p2 = rowsP[ir][2];
        float4 p3 = rowsP[ir][3];
        float2 tb = tbv[ir];
        float qa = EXP2(fmaf(tb.y, ua.y, tb.x * ua.x));
        float qb = EXP2(fmaf(tb.y, ub.y, tb.x * ub.x));
        float qc = EXP2(fmaf(tb.y, uc.y, tb.x * uc.x));
        float qd = EXP2(fmaf(tb.y, ud.y, tb.x * ud.x));
        float pk[16];
        *(float4*)&pk[0]  = p0; *(float4*)&pk[4]  = p1;
        *(float4*)&pk[8]  = p2; *(float4*)&pk[12] = p3;
#pragma unroll
        for (int k = 0; k < N_EMB; ++k) {
            sa[k]  = fmaf(pk[k], qa, sa[k]);
            sb[k]  = fmaf(pk[k], qb, sb[k]);
            sc_[k] = fmaf(pk[k], qc, sc_[k]);
            sd[k]  = fmaf(pk[k], qd, sd[k]);
        }
    }

    // ---------------- Phase C: cross-wave reduce; write-through part stores.
    // half 0: l-offsets [0,128)
#pragma unroll
    for (int k = 0; k < N_EMB; ++k) {
        red[w][k * 128 + lane]      = sa[k];
        red[w][k * 128 + 64 + lane] = sb[k];
    }
    __syncthreads();
#pragma unroll
    for (int r = 0; r < 2; ++r) {
        const int e  = (t + r * BLOCK) * 4;
        const float4 a0 = *(const float4*)&red[0][e];
        const float4 a1 = *(const float4*)&red[1][e];
        const float4 a2 = *(const float4*)&red[2][e];
        const float4 a3 = *(const float4*)&red[3][e];
        const int base = ib * M_TOT + (e >> 7) * EPS_N + l0 + (e & 127);
        WT_STORE_F(&part[base + 0], a0.x + a1.x + a2.x + a3.x);
        WT_STORE_F(&part[base + 1], a0.y + a1.y + a2.y + a3.y);
        WT_STORE_F(&part[base + 2], a0.z + a1.z + a2.z + a3.z);
        WT_STORE_F(&part[base + 3], a0.w + a1.w + a2.w + a3.w);
    }
    __syncthreads();                          // red consumed
    // half 1: l-offsets [128,256)
#pragma unroll
    for (int k = 0; k < N_EMB; ++k) {
        red[w][k * 128 + lane]      = sc_[k];
        red[w][k * 128 + 64 + lane] = sd[k];
    }
    __syncthreads();
#pragma unroll
    for (int r = 0; r < 2; ++r) {
        const int e  = (t + r * BLOCK) * 4;
        const float4 a0 = *(const float4*)&red[0][e];
        const float4 a1 = *(const float4*)&red[1][e];
        const float4 a2 = *(const float4*)&red[2][e];
        const float4 a3 = *(const float4*)&red[3][e];
        const int base = ib * M_TOT + (e >> 7) * EPS_N + l0 + 128 + (e & 127);
        WT_STORE_F(&part[base + 0], a0.x + a1.x + a2.x + a3.x);
        WT_STORE_F(&part[base + 1], a0.y + a1.y + a2.y + a3.y);
        WT_STORE_F(&part[base + 2], a0.z + a1.z + a2.z + a3.z);
        WT_STORE_F(&part[base + 3], a0.w + a1.w + a2.w + a3.w);
    }

    // ---------------- Column barrier (64 blocks of column c).
    VMCNT0();                                 // this wave's WT stores landed
    __syncthreads();                          // => all waves' stores landed
    if (t == 0)
        WT_STORE_U(&done[c * NICH + ib], MAGIC);
    if (w == 0) {                             // wave 0: lane monitors one flag
        for (;;) {
            unsigned int v = COH_LOAD_U(&done[c * NICH + lane]);
            if (__all(v == MAGIC)) break;
            __builtin_amdgcn_s_sleep(2);
        }
    }
    __syncthreads();                          // release waves 1-3
    if (w != 0) return;                       // phase 2 is wave-0-only

    // Acquire: invalidate stale L1/L2 so plain loads see write-through data.
    // Cheap here: L2 holds no dirty lines (everything was written through).
    __threadfence();

    // ---------------- Phase 2: this block combines its 64 j's.
    // j = k*1024 + l,  k = ib>>2,  l = l0 + (ib&3)*64 + lane.
    const int kk = ib >> 2;
    const int l  = l0 + (ib & 3) * 64 + lane;
    const int j  = kk * EPS_N + l;
    float S = 0.0f;
#pragma unroll 16
    for (int ibx = 0; ibx < NICH; ++ibx)      // fixed order: deterministic
        S += part[ibx * M_TOT + j];           // plain coalesced loads post-fence

    const float e0 = omT * emb[2 * kk]     + T * eps[2 * l];
    const float e1 = omT * emb[2 * kk + 1] + T * eps[2 * l + 1];
    const float g  = La * (e0 * e0 + e1 * e1);
    float v = g + LOG2F_(S);                  // lse_j / ln2

#pragma unroll
    for (int off = 32; off; off >>= 1) v += __shfl_down(v, off, 64);

    if (lane == 0) WT_STORE_F(&bsum[bidx], v);
    VMCNT0();                                 // bsum landed before flag
    if (lane == 0) WT_STORE_U(&fin[bidx], MAGIC);
    VMCNT0();                                 // flag landed before once-check

    // ---------------- Once-check election: the last block whose flag lands
    // necessarily observes all 256 set. Duplicate finishers are benign
    // (identical deterministic value).
    unsigned int f0 = COH_LOAD_U(&fin[lane]);
    unsigned int f1 = COH_LOAD_U(&fin[lane + 64]);
    unsigned int f2 = COH_LOAD_U(&fin[lane + 128]);
    unsigned int f3 = COH_LOAD_U(&fin[lane + 192]);
    if (!__all(f0 == MAGIC && f1 == MAGIC && f2 == MAGIC && f3 == MAGIC))
        return;

    float q0 = COH_LOAD_F(&bsum[lane]);
    float q1 = COH_LOAD_F(&bsum[lane + 64]);
    float q2 = COH_LOAD_F(&bsum[lane + 128]);
    float q3 = COH_LOAD_F(&bsum[lane + 192]);
    float q  = ((q0 + q1) + q2) + q3;         // fixed association
#pragma unroll
    for (int off = 32; off; off >>= 1) q += __shfl_down(q, off, 64);
    if (lane == 0) {
        const float sum_lse = q * LN2;        // sum_j lse_j
        // loss = -mean(lse) + 0.5*z_dim*(2*ls - 1) + log(n);  z_dim=2, n=8192
        out[0] = -sum_lse / (float)M_TOT + (2.0f * ls - 1.0f)
                 + 9.010913347279288f;
    }
}

extern "C" void kernel_launch(void* const* d_in, const int* in_sizes, int n_in,
                              void* d_out, int out_size, void* d_ws, size_t ws_size,
                              hipStream_t stream)
{
    const float* z    = (const float*)d_in[0];
    const float* emb  = (const float*)d_in[1];
    const float* lsig = (const float*)d_in[2];
    const float* eps  = (const float*)d_in[3];
    const float* temp = (const float*)d_in[4];

    // ws layout (poison-safe: no zero-init needed anywhere):
    // [0,1K) done flags, [1K,2K) fin flags, [2K,3K) bsum, [4K, 4K+4MB) part.
    unsigned int* done = (unsigned int*)d_ws;
    unsigned int* fin  = done + 256;
    float* bsum = (float*)(fin + 256);
    float* part = (float*)d_ws + 1024;             // byte offset 4096

    dim3 grid(NLCH, NICH);                         // 4 x 64 = 256 blocks (1/CU)
    fused_kernel<<<grid, BLOCK, 0, stream>>>(z, emb, lsig, eps, temp,
                                             part, bsum, done, fin,
                                             (float*)d_out);
}

// Round 7
// 73.460 us; speedup vs baseline: 1.0854x; 1.0854x over previous
//
#include <hip/hip_runtime.h>
#include <math.h>

// Problem constants (fixed by reference setup_inputs)
#define N_TOT 8192
#define M_TOT 16384
#define EPS_N 1024      // M / N_EMB
#define N_EMB 16

#define LOG2E 1.4426950408889634f
#define LN2   0.6931471805599453f
#define EXP2(x) __builtin_amdgcn_exp2f(x)   // v_exp_f32
#define LOG2F_(x) __builtin_amdgcn_logf(x)  // v_log_f32 (log2)

// K1 tiling: product-grid factorization e_j = m_k + T*u_l  (j = k*1024 + l)
//   t_ij = A_ik + B_il,  P=2^A (8192x16), Q=2^B (8192x1024), S_kl = sum_i P_ik Q_il
// Round-6 (re-run; infra flake last round): BLOCK=512 (8 waves) => 2 waves/SIMD
// for ds_read/exp latency hiding (round-4/5 lesson: 1 wave/SIMD exposes all
// LDS+trans latency; fused/global-sync structures all lost to 2-dispatch).
#define BLOCK 512
#define IC    128            // i's per block
#define NICH  (N_TOT / IC)   // 64 i-chunks
#define LCH   256            // l's per block
#define NLCH  (EPS_N / LCH)  // 4 l-chunks

// Kernel 1: gemm partials. Plain stores only — kernel boundary provides
// coherence. Also zeroes the k2 election counter (saves a memset dispatch).
__global__ __launch_bounds__(BLOCK) void gemm_partial_kernel(
    const float* __restrict__ z, const float* __restrict__ emb,
    const float* __restrict__ log_sigma, const float* __restrict__ eps,
    const float* __restrict__ temperature, float* __restrict__ part,
    unsigned int* __restrict__ cnt)
{
    __shared__ float4 rowsP[IC][4];          // 8 KB: P[i][k] as 4 float4s
    __shared__ float2 tbv[IC];               // 1 KB: (T*b0, T*b1) per i
    __shared__ float  red[8][N_EMB * 128];   // 64 KB, reused for two l-halves

    const int t  = threadIdx.x;
    const int l0 = blockIdx.x * LCH;
    const int ib = blockIdx.y;

    if (t == 0 && blockIdx.x == 0 && blockIdx.y == 0)
        cnt[0] = 0u;                         // visible to k2 via kernel-boundary release

    const float ls = log_sigma[0];
    const float T  = temperature[0];
    const float alpha = -0.5f * EXP2(LOG2E * (-2.0f * ls));  // -1/(2 sigma^2)
    const float La  = LOG2E * alpha;
    const float omT = 1.0f - T;

    // Phase A: stage P-rows. 512 threads cover 128 i's x 4 k-quads (4 exps each).
    {
        const int il = t & (IC - 1);
        const int kq = t >> 7;               // 0..3, wave-uniform
        const int i  = ib * IC + il;
        const float2 zi = ((const float2*)z)[i];     // vector load
        const float c  = La * (zi.x * zi.x + zi.y * zi.y);
        const float b0 = -2.0f * La * zi.x, b1 = -2.0f * La * zi.y;
        float4 pa;
#pragma unroll
        for (int kk = 0; kk < 4; ++kk) {
            int k = kq * 4 + kk;
            float m0 = omT * emb[2 * k], m1 = omT * emb[2 * k + 1];
            ((float*)&pa)[kk] = EXP2(c + b0 * m0 + b1 * m1);   // P_ik
        }
        rowsP[il][kq] = pa;
        if (kq == 0)
            tbv[il] = make_float2(T * b0, T * b1);
    }

    // Each lane owns 4 l's: l0+lane, +64, +128, +192 (coalesced float2 loads)
    const int lane = t & 63;
    const int w    = t >> 6;                 // 0..7
    const float2* eps2 = (const float2*)eps;
    const float2 ua = eps2[l0 + lane];
    const float2 ub = eps2[l0 + 64 + lane];
    const float2 uc = eps2[l0 + 128 + lane];
    const float2 ud = eps2[l0 + 192 + lane];

    __syncthreads();

    float sa[N_EMB] = {0.0f};
    float sb[N_EMB] = {0.0f};
    float sc_[N_EMB] = {0.0f};
    float sd[N_EMB] = {0.0f};
    // 8 waves partition the 128 i-rows (16 each); rowsP/tbv reads are
    // wave-uniform (broadcast). 64 FMAs per (4x ds_read_b128 + 1x ds_read_b64).
#pragma unroll 2
    for (int n = 0; n < IC / 8; ++n) {
        const int ir = w * (IC / 8) + n;
        float4 p0 = rowsP[ir][0];
        float4 p1 = rowsP[ir][1];
        float4 p2 = rowsP[ir][2];
        float4 p3 = rowsP[ir][3];
        float2 tb = tbv[ir];
        float qa = EXP2(fmaf(tb.y, ua.y, tb.x * ua.x));   // Q_i,l
        float qb = EXP2(fmaf(tb.y, ub.y, tb.x * ub.x));
        float qc = EXP2(fmaf(tb.y, uc.y, tb.x * uc.x));
        float qd = EXP2(fmaf(tb.y, ud.y, tb.x * ud.x));
        float pk[16];
        *(float4*)&pk[0]  = p0; *(float4*)&pk[4]  = p1;
        *(float4*)&pk[8]  = p2; *(float4*)&pk[12] = p3;
#pragma unroll
        for (int k = 0; k < N_EMB; ++k) {
            sa[k]  = fmaf(pk[k], qa, sa[k]);
            sb[k]  = fmaf(pk[k], qb, sb[k]);
            sc_[k] = fmaf(pk[k], qc, sc_[k]);
            sd[k]  = fmaf(pk[k], qd, sd[k]);
        }
    }

    // Phase C: cross-wave reduce via LDS, two 128-l halves (red reused).
    // Reduce reads are float4-vectorized (linear layout: conflict-free);
    // part stores are dwordx4.  512 threads x 1 float4 covers 2048 floats.
    // half 0: l-offsets [0,128) = sa (lane) + sb (lane+64)
#pragma unroll
    for (int k = 0; k < N_EMB; ++k) {
        red[w][k * 128 + lane]      = sa[k];
        red[w][k * 128 + 64 + lane] = sb[k];
    }
    __syncthreads();
    {
        const int e = t * 4;
        float4 S = *(const float4*)&red[0][e];
#pragma unroll
        for (int ww = 1; ww < 8; ++ww) {
            const float4 a = *(const float4*)&red[ww][e];
            S.x += a.x; S.y += a.y; S.z += a.z; S.w += a.w;
        }
        const int base = ib * M_TOT + (e >> 7) * EPS_N + l0 + (e & 127);
        *(float4*)&part[base] = S;
    }
    __syncthreads();                          // red consumed; safe to overwrite
    // half 1: l-offsets [128,256) = sc_ (lane) + sd (lane+64)
#pragma unroll
    for (int k = 0; k < N_EMB; ++k) {
        red[w][k * 128 + lane]      = sc_[k];
        red[w][k * 128 + 64 + lane] = sd[k];
    }
    __syncthreads();
    {
        const int e = t * 4;
        float4 S = *(const float4*)&red[0][e];
#pragma unroll
        for (int ww = 1; ww < 8; ++ww) {
            const float4 a = *(const float4*)&red[ww][e];
            S.x += a.x; S.y += a.y; S.z += a.z; S.w += a.w;
        }
        const int base = ib * M_TOT + (e >> 7) * EPS_N + l0 + 128 + (e & 127);
        *(float4*)&part[base] = S;
    }
}

// Kernel 2: per-j combine + in-kernel final election (proven round 2/4).
// Round-6: 256 blocks (was 64 — 3/4 of CUs idle) x 64 j's each; the 64
// ib-partials per j are wave-sliced 4 ways (16 loads/thread) to cut the
// serial load chain, then 4-way LDS combine.
#define K2BLOCK 256
__global__ __launch_bounds__(K2BLOCK) void reduce_final_kernel(
    const float* __restrict__ emb, const float* __restrict__ log_sigma,
    const float* __restrict__ eps, const float* __restrict__ temperature,
    const float* __restrict__ part, float* __restrict__ bsum,
    unsigned int* __restrict__ cnt, float* __restrict__ out)
{
    const int lane = threadIdx.x & 63;
    const int w    = threadIdx.x >> 6;        // 0..3 = ib-slice
    const int j    = blockIdx.x * 64 + lane;  // 64 j's per block

    const float ls = log_sigma[0];
    const float T  = temperature[0];
    const float alpha = -0.5f * EXP2(LOG2E * (-2.0f * ls));

    float Sp = 0.0f;
#pragma unroll
    for (int n = 0; n < NICH / 4; ++n)        // 16 independent loads, coalesced
        Sp += part[(w * (NICH / 4) + n) * M_TOT + j];

    __shared__ float red2[4][64];
    __shared__ unsigned int sdone;
    red2[w][lane] = Sp;
    __syncthreads();

    // All waves redundantly compute the same 64 v_j (cheap; keeps code uniform)
    const float S = ((red2[0][lane] + red2[1][lane]) + red2[2][lane]) + red2[3][lane];
    const int k = j >> 10, l = j & (EPS_N - 1);
    const float omT = 1.0f - T;
    const float e0 = omT * emb[2 * k]     + T * eps[2 * l];
    const float e1 = omT * emb[2 * k + 1] + T * eps[2 * l + 1];
    const float g  = LOG2E * alpha * (e0 * e0 + e1 * e1);  // factored-out 2^g
    float v = g + LOG2F_(S);                  // lse_j / ln2
#pragma unroll
    for (int off = 32; off; off >>= 1) v += __shfl_down(v, off, 64);

    if (threadIdx.x == 0) {
        // Write-through store to the coherent point (agent scope => sc0 sc1).
        __hip_atomic_store(&bsum[blockIdx.x], v, __ATOMIC_RELAXED,
                           __HIP_MEMORY_SCOPE_AGENT);
        // bsum store must land before the counter bump becomes visible.
        asm volatile("s_waitcnt vmcnt(0)" ::: "memory");
        const unsigned int old = __hip_atomic_fetch_add(
            &cnt[0], 1u, __ATOMIC_RELAXED, __HIP_MEMORY_SCOPE_AGENT);
        sdone = (old == (unsigned int)(M_TOT / 64 - 1)) ? 1u : 0u;
    }
    __syncthreads();
    if (sdone == 0u) return;                  // not the last block

    // Last block: wave 0 sums the 256 block sums (fixed order: deterministic)
    if (threadIdx.x < 64) {
        float q0 = __hip_atomic_load(&bsum[lane],       __ATOMIC_RELAXED, __HIP_MEMORY_SCOPE_AGENT);
        float q1 = __hip_atomic_load(&bsum[lane + 64],  __ATOMIC_RELAXED, __HIP_MEMORY_SCOPE_AGENT);
        float q2 = __hip_atomic_load(&bsum[lane + 128], __ATOMIC_RELAXED, __HIP_MEMORY_SCOPE_AGENT);
        float q3 = __hip_atomic_load(&bsum[lane + 192], __ATOMIC_RELAXED, __HIP_MEMORY_SCOPE_AGENT);
        float q  = ((q0 + q1) + q2) + q3;     // fixed association
#pragma unroll
        for (int off = 32; off; off >>= 1) q += __shfl_down(q, off, 64);
        if (lane == 0) {
            const float sum_lse = q * LN2;    // sum_j lse_j
            // loss = -mean(lse) + 0.5*z_dim*(2*ls - 1) + log(n);  z_dim=2, n=8192
            out[0] = -sum_lse / (float)M_TOT + (2.0f * ls - 1.0f)
                     + 9.010913347279288f;
        }
    }
}

extern "C" void kernel_launch(void* const* d_in, const int* in_sizes, int n_in,
                              void* d_out, int out_size, void* d_ws, size_t ws_size,
                              hipStream_t stream)
{
    const float* z    = (const float*)d_in[0];
    const float* emb  = (const float*)d_in[1];
    const float* lsig = (const float*)d_in[2];
    const float* eps  = (const float*)d_in[3];
    const float* temp = (const float*)d_in[4];

    // ws layout: [0,64) counter (zeroed by k1), [64,1088) bsum (256 floats,
    // fully overwritten before read), [2048, 2048+4MB) part.
    unsigned int* cnt = (unsigned int*)d_ws;
    float* bsum = (float*)d_ws + 16;               // byte offset 64
    float* part = (float*)d_ws + 512;              // byte offset 2048

    dim3 grid1(NLCH, NICH);                        // 4 x 64 = 256 blocks (1/CU)
    gemm_partial_kernel<<<grid1, BLOCK, 0, stream>>>(z, emb, lsig, eps, temp,
                                                     part, cnt);
    reduce_final_kernel<<<M_TOT / 64, K2BLOCK, 0, stream>>>(
        emb, lsig, eps, temp, part, bsum, cnt, (float*)d_out);
}

// Round 8
// 72.668 us; speedup vs baseline: 1.0972x; 1.0109x over previous
//
#include <hip/hip_runtime.h>
#include <math.h>

// Problem constants (fixed by reference setup_inputs)
#define N_TOT 8192
#define M_TOT 16384
#define EPS_N 1024      // M / N_EMB
#define N_EMB 16

#define LOG2E 1.4426950408889634f
#define LN2   0.6931471805599453f
#define EXP2(x) __builtin_amdgcn_exp2f(x)   // v_exp_f32
#define LOG2F_(x) __builtin_amdgcn_logf(x)  // v_log_f32 (log2)

// K1 tiling: product-grid factorization e_j = m_k + T*u_l  (j = k*1024 + l)
//   t_ij = A_ik + B_il,  P=2^A (8192x16), Q=2^B (8192x1024), S_kl = sum_i P_ik Q_il
// Round-8: k1 is the EXACT round-4 kernel (best measured: 71.8). Only k2
// changes (64 -> 256 blocks), isolating the one untested half of round 6/7.
#define BLOCK 256
#define IC    128            // i's per block
#define NICH  (N_TOT / IC)   // 64 i-chunks
#define LCH   256            // l's per block
#define NLCH  (EPS_N / LCH)  // 4 l-chunks

// Kernel 1: gemm partials (byte-identical to round 4). Plain stores only —
// kernel boundary provides coherence. Zeroes the k2 election counter.
__global__ __launch_bounds__(BLOCK) void gemm_partial_kernel(
    const float* __restrict__ z, const float* __restrict__ emb,
    const float* __restrict__ log_sigma, const float* __restrict__ eps,
    const float* __restrict__ temperature, float* __restrict__ part,
    unsigned int* __restrict__ cnt)
{
    __shared__ float4 rowsP[IC][4];          // 8 KB: P[i][k] as 4 float4s
    __shared__ float2 tbv[IC];               // 1 KB: (T*b0, T*b1) per i -> ds_read_b64
    __shared__ float  red[4][N_EMB * 128];   // 32 KB, reused for two l-halves

    const int t  = threadIdx.x;
    const int l0 = blockIdx.x * LCH;
    const int ib = blockIdx.y;

    if (t == 0 && blockIdx.x == 0 && blockIdx.y == 0)
        cnt[0] = 0u;                         // visible to k2 via kernel-boundary release

    const float ls = log_sigma[0];
    const float T  = temperature[0];
    const float alpha = -0.5f * EXP2(LOG2E * (-2.0f * ls));  // -1/(2 sigma^2)
    const float La  = LOG2E * alpha;
    const float omT = 1.0f - T;

    // Phase A: stage P-rows. 256 threads cover 128 i's x 2 k-halves (8 exps each).
    {
        const int il = t & (IC - 1);
        const int kh = t >> 7;               // wave-uniform (waves 0,1 -> 0; 2,3 -> 1)
        const int i  = ib * IC + il;
        const float z0 = z[2 * i], z1 = z[2 * i + 1];
        const float c  = La * (z0 * z0 + z1 * z1);
        const float b0 = -2.0f * La * z0, b1 = -2.0f * La * z1;
        float4 pa, pb;
#pragma unroll
        for (int kk = 0; kk < 4; ++kk) {
            int k = kh * 8 + kk;
            float m0 = omT * emb[2 * k], m1 = omT * emb[2 * k + 1];
            ((float*)&pa)[kk] = EXP2(c + b0 * m0 + b1 * m1);   // P_ik
        }
#pragma unroll
        for (int kk = 0; kk < 4; ++kk) {
            int k = kh * 8 + 4 + kk;
            float m0 = omT * emb[2 * k], m1 = omT * emb[2 * k + 1];
            ((float*)&pb)[kk] = EXP2(c + b0 * m0 + b1 * m1);
        }
        rowsP[il][kh * 2]     = pa;
        rowsP[il][kh * 2 + 1] = pb;
        if (kh == 0)
            tbv[il] = make_float2(T * b0, T * b1);
    }

    // Each lane owns 4 l's: l0+lane, +64, +128, +192 (coalesced float2 loads)
    const int lane = t & 63;
    const int w    = t >> 6;
    const float2* eps2 = (const float2*)eps;
    const float2 ua = eps2[l0 + lane];
    const float2 ub = eps2[l0 + 64 + lane];
    const float2 uc = eps2[l0 + 128 + lane];
    const float2 ud = eps2[l0 + 192 + lane];

    __syncthreads();

    float sa[N_EMB] = {0.0f};
    float sb[N_EMB] = {0.0f};
    float sc_[N_EMB] = {0.0f};
    float sd[N_EMB] = {0.0f};
    // Each wave reduces its private 32-i subrange; rowsP/tbv reads are
    // wave-uniform (broadcast). 64 FMAs per (4x ds_read_b128 + 1x ds_read_b64).
#pragma unroll 2
    for (int n = 0; n < IC / 4; ++n) {
        const int ir = w * (IC / 4) + n;
        float4 p0 = rowsP[ir][0];
        float4 p1 = rowsP[ir][1];
        float4 p2 = rowsP[ir][2];
        float4 p3 = rowsP[ir][3];
        float2 tb = tbv[ir];
        float qa = EXP2(fmaf(tb.y, ua.y, tb.x * ua.x));   // Q_i,l
        float qb = EXP2(fmaf(tb.y, ub.y, tb.x * ub.x));
        float qc = EXP2(fmaf(tb.y, uc.y, tb.x * uc.x));
        float qd = EXP2(fmaf(tb.y, ud.y, tb.x * ud.x));
        float pk[16];
        *(float4*)&pk[0]  = p0; *(float4*)&pk[4]  = p1;
        *(float4*)&pk[8]  = p2; *(float4*)&pk[12] = p3;
#pragma unroll
        for (int k = 0; k < N_EMB; ++k) {
            sa[k]  = fmaf(pk[k], qa, sa[k]);
            sb[k]  = fmaf(pk[k], qb, sb[k]);
            sc_[k] = fmaf(pk[k], qc, sc_[k]);
            sd[k]  = fmaf(pk[k], qd, sd[k]);
        }
    }

    // Phase C: cross-wave reduce via LDS, two 128-l halves (red reused).
    // Reduce reads are float4-vectorized (linear layout: conflict-free) and
    // part stores are dwordx4.
    // half 0: l-offsets [0,128) = sa (lane) + sb (lane+64)
#pragma unroll
    for (int k = 0; k < N_EMB; ++k) {
        red[w][k * 128 + lane]      = sa[k];
        red[w][k * 128 + 64 + lane] = sb[k];
    }
    __syncthreads();
#pragma unroll
    for (int r = 0; r < 2; ++r) {
        const int eq = t + r * BLOCK;         // quad index, 512 quads
        const int e  = eq * 4;
        const float4 a0 = *(const float4*)&red[0][e];
        const float4 a1 = *(const float4*)&red[1][e];
        const float4 a2 = *(const float4*)&red[2][e];
        const float4 a3 = *(const float4*)&red[3][e];
        float4 S;
        S.x = a0.x + a1.x + a2.x + a3.x;
        S.y = a0.y + a1.y + a2.y + a3.y;
        S.z = a0.z + a1.z + a2.z + a3.z;
        S.w = a0.w + a1.w + a2.w + a3.w;
        const int k  = e >> 7;
        const int ll = e & 127;               // multiple of 4; quad stays in-row
        *(float4*)&part[ib * M_TOT + k * EPS_N + l0 + ll] = S;
    }
    __syncthreads();                          // red consumed; safe to overwrite
    // half 1: l-offsets [128,256) = sc_ (lane) + sd (lane+64)
#pragma unroll
    for (int k = 0; k < N_EMB; ++k) {
        red[w][k * 128 + lane]      = sc_[k];
        red[w][k * 128 + 64 + lane] = sd[k];
    }
    __syncthreads();
#pragma unroll
    for (int r = 0; r < 2; ++r) {
        const int eq = t + r * BLOCK;
        const int e  = eq * 4;
        const float4 a0 = *(const float4*)&red[0][e];
        const float4 a1 = *(const float4*)&red[1][e];
        const float4 a2 = *(const float4*)&red[2][e];
        const float4 a3 = *(const float4*)&red[3][e];
        float4 S;
        S.x = a0.x + a1.x + a2.x + a3.x;
        S.y = a0.y + a1.y + a2.y + a3.y;
        S.z = a0.z + a1.z + a2.z + a3.z;
        S.w = a0.w + a1.w + a2.w + a3.w;
        const int k  = e >> 7;
        const int ll = e & 127;
        *(float4*)&part[ib * M_TOT + k * EPS_N + l0 + 128 + ll] = S;
    }
}

// Kernel 2: per-j combine + in-kernel final election. Round-8 change (the
// isolated half of round 6): 256 blocks (was 64 — 3/4 of CUs idle) x 64 j's
// each; the 64 ib-partials per j are wave-sliced 4 ways (16 loads/thread),
// then 4-way LDS combine. Election pattern proven rounds 2/4/7.
#define K2BLOCK 256
__global__ __launch_bounds__(K2BLOCK) void reduce_final_kernel(
    const float* __restrict__ emb, const float* __restrict__ log_sigma,
    const float* __restrict__ eps, const float* __restrict__ temperature,
    const float* __restrict__ part, float* __restrict__ bsum,
    unsigned int* __restrict__ cnt, float* __restrict__ out)
{
    const int lane = threadIdx.x & 63;
    const int w    = threadIdx.x >> 6;        // 0..3 = ib-slice
    const int j    = blockIdx.x * 64 + lane;  // 64 j's per block

    const float ls = log_sigma[0];
    const float T  = temperature[0];
    const float alpha = -0.5f * EXP2(LOG2E * (-2.0f * ls));

    float Sp = 0.0f;
#pragma unroll
    for (int n = 0; n < NICH / 4; ++n)        // 16 independent loads, coalesced
        Sp += part[(w * (NICH / 4) + n) * M_TOT + j];

    __shared__ float red2[4][64];
    __shared__ unsigned int sdone;
    red2[w][lane] = Sp;
    __syncthreads();

    // All waves redundantly compute the same 64 v_j (cheap; keeps code uniform)
    const float S = ((red2[0][lane] + red2[1][lane]) + red2[2][lane]) + red2[3][lane];
    const int k = j >> 10, l = j & (EPS_N - 1);
    const float omT = 1.0f - T;
    const float e0 = omT * emb[2 * k]     + T * eps[2 * l];
    const float e1 = omT * emb[2 * k + 1] + T * eps[2 * l + 1];
    const float g  = LOG2E * alpha * (e0 * e0 + e1 * e1);  // factored-out 2^g
    float v = g + LOG2F_(S);                  // lse_j / ln2
#pragma unroll
    for (int off = 32; off; off >>= 1) v += __shfl_down(v, off, 64);

    if (threadIdx.x == 0) {
        // Write-through store to the coherent point (agent scope => sc0 sc1).
        __hip_atomic_store(&bsum[blockIdx.x], v, __ATOMIC_RELAXED,
                           __HIP_MEMORY_SCOPE_AGENT);
        // bsum store must land before the counter bump becomes visible.
        asm volatile("s_waitcnt vmcnt(0)" ::: "memory");
        const unsigned int old = __hip_atomic_fetch_add(
            &cnt[0], 1u, __ATOMIC_RELAXED, __HIP_MEMORY_SCOPE_AGENT);
        sdone = (old == (unsigned int)(M_TOT / 64 - 1)) ? 1u : 0u;
    }
    __syncthreads();
    if (sdone == 0u) return;                  // not the last block

    // Last block: wave 0 sums the 256 block sums (fixed order: deterministic)
    if (threadIdx.x < 64) {
        float q0 = __hip_atomic_load(&bsum[lane],       __ATOMIC_RELAXED, __HIP_MEMORY_SCOPE_AGENT);
        float q1 = __hip_atomic_load(&bsum[lane + 64],  __ATOMIC_RELAXED, __HIP_MEMORY_SCOPE_AGENT);
        float q2 = __hip_atomic_load(&bsum[lane + 128], __ATOMIC_RELAXED, __HIP_MEMORY_SCOPE_AGENT);
        float q3 = __hip_atomic_load(&bsum[lane + 192], __ATOMIC_RELAXED, __HIP_MEMORY_SCOPE_AGENT);
        float q  = ((q0 + q1) + q2) + q3;     // fixed association
#pragma unroll
        for (int off = 32; off; off >>= 1) q += __shfl_down(q, off, 64);
        if (lane == 0) {
            const float sum_lse = q * LN2;    // sum_j lse_j
            // loss = -mean(lse) + 0.5*z_dim*(2*ls - 1) + log(n);  z_dim=2, n=8192
            out[0] = -sum_lse / (float)M_TOT + (2.0f * ls - 1.0f)
                     + 9.010913347279288f;
        }
    }
}

extern "C" void kernel_launch(void* const* d_in, const int* in_sizes, int n_in,
                              void* d_out, int out_size, void* d_ws, size_t ws_size,
                              hipStream_t stream)
{
    const float* z    = (const float*)d_in[0];
    const float* emb  = (const float*)d_in[1];
    const float* lsig = (const float*)d_in[2];
    const float* eps  = (const float*)d_in[3];
    const float* temp = (const float*)d_in[4];

    // ws layout: [0,64) counter (zeroed by k1), [64,1088) bsum (256 floats,
    // fully overwritten before read), [2048, 2048+4MB) part.
    unsigned int* cnt = (unsigned int*)d_ws;
    float* bsum = (float*)d_ws + 16;               // byte offset 64
    float* part = (float*)d_ws + 512;              // byte offset 2048

    dim3 grid1(NLCH, NICH);                        // 4 x 64 = 256 blocks (1/CU)
    gemm_partial_kernel<<<grid1, BLOCK, 0, stream>>>(z, emb, lsig, eps, temp,
                                                     part, cnt);
    reduce_final_kernel<<<M_TOT / 64, K2BLOCK, 0, stream>>>(
        emb, lsig, eps, temp, part, bsum, cnt, (float*)d_out);
}

// Round 9
// 72.515 us; speedup vs baseline: 1.0996x; 1.0021x over previous
//
#include <hip/hip_runtime.h>
#include <math.h>

// Problem constants (fixed by reference setup_inputs)
#define N_TOT 8192
#define M_TOT 16384
#define EPS_N 1024      // M / N_EMB
#define N_EMB 16

#define LOG2E 1.4426950408889634f
#define LN2   0.6931471805599453f
#define EXP2(x) __builtin_amdgcn_exp2f(x)   // v_exp_f32
#define LOG2F_(x) __builtin_amdgcn_logf(x)  // v_log_f32 (log2)

// K1 tiling: product-grid factorization e_j = m_k + T*u_l  (j = k*1024 + l)
//   t_ij = A_ik + B_il,  P=2^A (8192x16), Q=2^B (8192x1024), S_kl = sum_i P_ik Q_il
// TERMINAL CONFIG (round 9 = exact round-4 pair, best measured 71.8 µs):
//   - 2 dispatches (fusion regressed twice: R1 +30 µs, R5 +8 µs — intra-kernel
//     global sync costs more than a kernel boundary on gfx950)
//   - k1: LCH=256 (4 l's/lane), IC=128, BLOCK=256, grid 4x64=256 blocks (1/CU)
//     (BLOCK=512 measured +0.8 µs in R7; LCH=128 variants measured slower)
//   - k2: 64 blocks x 256 threads (256-block variant measured +0.85 µs in R8)
#define BLOCK 256
#define IC    128            // i's per block
#define NICH  (N_TOT / IC)   // 64 i-chunks
#define LCH   256            // l's per block
#define NLCH  (EPS_N / LCH)  // 4 l-chunks

// Kernel 1: gemm partials. Plain stores only — kernel boundary provides
// coherence. Also zeroes the k2 election counter (saves the memset dispatch).
__global__ __launch_bounds__(BLOCK) void gemm_partial_kernel(
    const float* __restrict__ z, const float* __restrict__ emb,
    const float* __restrict__ log_sigma, const float* __restrict__ eps,
    const float* __restrict__ temperature, float* __restrict__ part,
    unsigned int* __restrict__ cnt)
{
    __shared__ float4 rowsP[IC][4];          // 8 KB: P[i][k] as 4 float4s
    __shared__ float2 tbv[IC];               // 1 KB: (T*b0, T*b1) per i -> ds_read_b64
    __shared__ float  red[4][N_EMB * 128];   // 32 KB, reused for two l-halves

    const int t  = threadIdx.x;
    const int l0 = blockIdx.x * LCH;
    const int ib = blockIdx.y;

    if (t == 0 && blockIdx.x == 0 && blockIdx.y == 0)
        cnt[0] = 0u;                         // visible to k2 via kernel-boundary release

    const float ls = log_sigma[0];
    const float T  = temperature[0];
    const float alpha = -0.5f * EXP2(LOG2E * (-2.0f * ls));  // -1/(2 sigma^2)
    const float La  = LOG2E * alpha;
    const float omT = 1.0f - T;

    // Phase A: stage P-rows. 256 threads cover 128 i's x 2 k-halves (8 exps each).
    {
        const int il = t & (IC - 1);
        const int kh = t >> 7;               // wave-uniform (waves 0,1 -> 0; 2,3 -> 1)
        const int i  = ib * IC + il;
        const float z0 = z[2 * i], z1 = z[2 * i + 1];
        const float c  = La * (z0 * z0 + z1 * z1);
        const float b0 = -2.0f * La * z0, b1 = -2.0f * La * z1;
        float4 pa, pb;
#pragma unroll
        for (int kk = 0; kk < 4; ++kk) {
            int k = kh * 8 + kk;
            float m0 = omT * emb[2 * k], m1 = omT * emb[2 * k + 1];
            ((float*)&pa)[kk] = EXP2(c + b0 * m0 + b1 * m1);   // P_ik
        }
#pragma unroll
        for (int kk = 0; kk < 4; ++kk) {
            int k = kh * 8 + 4 + kk;
            float m0 = omT * emb[2 * k], m1 = omT * emb[2 * k + 1];
            ((float*)&pb)[kk] = EXP2(c + b0 * m0 + b1 * m1);
        }
        rowsP[il][kh * 2]     = pa;
        rowsP[il][kh * 2 + 1] = pb;
        if (kh == 0)
            tbv[il] = make_float2(T * b0, T * b1);
    }

    // Each lane owns 4 l's: l0+lane, +64, +128, +192 (coalesced float2 loads)
    const int lane = t & 63;
    const int w    = t >> 6;
    const float2* eps2 = (const float2*)eps;
    const float2 ua = eps2[l0 + lane];
    const float2 ub = eps2[l0 + 64 + lane];
    const float2 uc = eps2[l0 + 128 + lane];
    const float2 ud = eps2[l0 + 192 + lane];

    __syncthreads();

    float sa[N_EMB] = {0.0f};
    float sb[N_EMB] = {0.0f};
    float sc_[N_EMB] = {0.0f};
    float sd[N_EMB] = {0.0f};
    // Each wave reduces its private 32-i subrange; rowsP/tbv reads are
    // wave-uniform (broadcast). 64 FMAs per (4x ds_read_b128 + 1x ds_read_b64).
#pragma unroll 2
    for (int n = 0; n < IC / 4; ++n) {
        const int ir = w * (IC / 4) + n;
        float4 p0 = rowsP[ir][0];
        float4 p1 = rowsP[ir][1];
        float4 p2 = rowsP[ir][2];
        float4 p3 = rowsP[ir][3];
        float2 tb = tbv[ir];
        float qa = EXP2(fmaf(tb.y, ua.y, tb.x * ua.x));   // Q_i,l
        float qb = EXP2(fmaf(tb.y, ub.y, tb.x * ub.x));
        float qc = EXP2(fmaf(tb.y, uc.y, tb.x * uc.x));
        float qd = EXP2(fmaf(tb.y, ud.y, tb.x * ud.x));
        float pk[16];
        *(float4*)&pk[0]  = p0; *(float4*)&pk[4]  = p1;
        *(float4*)&pk[8]  = p2; *(float4*)&pk[12] = p3;
#pragma unroll
        for (int k = 0; k < N_EMB; ++k) {
            sa[k]  = fmaf(pk[k], qa, sa[k]);
            sb[k]  = fmaf(pk[k], qb, sb[k]);
            sc_[k] = fmaf(pk[k], qc, sc_[k]);
            sd[k]  = fmaf(pk[k], qd, sd[k]);
        }
    }

    // Phase C: cross-wave reduce via LDS, two 128-l halves (red reused).
    // Reduce reads are float4-vectorized (linear layout: conflict-free) and
    // part stores are dwordx4.
    // half 0: l-offsets [0,128) = sa (lane) + sb (lane+64)
#pragma unroll
    for (int k = 0; k < N_EMB; ++k) {
        red[w][k * 128 + lane]      = sa[k];
        red[w][k * 128 + 64 + lane] = sb[k];
    }
    __syncthreads();
#pragma unroll
    for (int r = 0; r < 2; ++r) {
        const int eq = t + r * BLOCK;         // quad index, 512 quads
        const int e  = eq * 4;
        const float4 a0 = *(const float4*)&red[0][e];
        const float4 a1 = *(const float4*)&red[1][e];
        const float4 a2 = *(const float4*)&red[2][e];
        const float4 a3 = *(const float4*)&red[3][e];
        float4 S;
        S.x = a0.x + a1.x + a2.x + a3.x;
        S.y = a0.y + a1.y + a2.y + a3.y;
        S.z = a0.z + a1.z + a2.z + a3.z;
        S.w = a0.w + a1.w + a2.w + a3.w;
        const int k  = e >> 7;
        const int ll = e & 127;               // multiple of 4; quad stays in-row
        *(float4*)&part[ib * M_TOT + k * EPS_N + l0 + ll] = S;
    }
    __syncthreads();                          // red consumed; safe to overwrite
    // half 1: l-offsets [128,256) = sc_ (lane) + sd (lane+64)
#pragma unroll
    for (int k = 0; k < N_EMB; ++k) {
        red[w][k * 128 + lane]      = sc_[k];
        red[w][k * 128 + 64 + lane] = sd[k];
    }
    __syncthreads();
#pragma unroll
    for (int r = 0; r < 2; ++r) {
        const int eq = t + r * BLOCK;
        const int e  = eq * 4;
        const float4 a0 = *(const float4*)&red[0][e];
        const float4 a1 = *(const float4*)&red[1][e];
        const float4 a2 = *(const float4*)&red[2][e];
        const float4 a3 = *(const float4*)&red[3][e];
        float4 S;
        S.x = a0.x + a1.x + a2.x + a3.x;
        S.y = a0.y + a1.y + a2.y + a3.y;
        S.z = a0.z + a1.z + a2.z + a3.z;
        S.w = a0.w + a1.w + a2.w + a3.w;
        const int k  = e >> 7;
        const int ll = e & 127;
        *(float4*)&part[ib * M_TOT + k * EPS_N + l0 + 128 + ll] = S;
    }
}

// Kernel 2: per-j combine + in-kernel final election (proven round 2/4).
// Only cross-block data INSIDE this kernel: 64 bsum floats + 1 counter, moved
// with agent-scope write-through atomics (sc0/sc1) — no L2 writeback fence.
__global__ __launch_bounds__(BLOCK) void reduce_final_kernel(
    const float* __restrict__ emb, const float* __restrict__ log_sigma,
    const float* __restrict__ eps, const float* __restrict__ temperature,
    const float* __restrict__ part, float* __restrict__ bsum,
    unsigned int* __restrict__ cnt, float* __restrict__ out)
{
    const int j = blockIdx.x * BLOCK + threadIdx.x;
    const float ls = log_sigma[0];
    const float T  = temperature[0];
    const float alpha = -0.5f * EXP2(LOG2E * (-2.0f * ls));

    float S = 0.0f;
#pragma unroll 16
    for (int ib = 0; ib < NICH; ++ib)
        S += part[ib * M_TOT + j];        // coalesced across threads

    const int k = j >> 10, l = j & (EPS_N - 1);
    const float omT = 1.0f - T;
    const float e0 = omT * emb[2 * k]     + T * eps[2 * l];
    const float e1 = omT * emb[2 * k + 1] + T * eps[2 * l + 1];
    const float g  = LOG2E * alpha * (e0 * e0 + e1 * e1);  // factored-out 2^g

    float v = g + LOG2F_(S);              // lse_j / ln2

#pragma unroll
    for (int off = 32; off; off >>= 1) v += __shfl_down(v, off, 64);
    __shared__ float wsum[BLOCK / 64];
    __shared__ unsigned int sdone;
    const int lane = threadIdx.x & 63, w = threadIdx.x >> 6;
    if (lane == 0) wsum[w] = v;
    __syncthreads();

    if (threadIdx.x == 0) {
        const float b = wsum[0] + wsum[1] + wsum[2] + wsum[3];
        // Write-through store to the coherent point (agent scope => sc0 sc1).
        __hip_atomic_store(&bsum[blockIdx.x], b, __ATOMIC_RELAXED,
                           __HIP_MEMORY_SCOPE_AGENT);
        // bsum store must land before the counter bump becomes visible.
        asm volatile("s_waitcnt vmcnt(0)" ::: "memory");
        const unsigned int old = __hip_atomic_fetch_add(
            &cnt[0], 1u, __ATOMIC_RELAXED, __HIP_MEMORY_SCOPE_AGENT);
        sdone = (old == (unsigned int)(M_TOT / BLOCK - 1)) ? 1u : 0u;
    }
    __syncthreads();
    if (sdone == 0u) return;              // not the last block

    // Last block: wave 0 sums the 64 block sums (fixed lane order: deterministic)
    if (threadIdx.x < 64) {
        float v2 = __hip_atomic_load(&bsum[threadIdx.x], __ATOMIC_RELAXED,
                                     __HIP_MEMORY_SCOPE_AGENT);
#pragma unroll
        for (int off = 32; off; off >>= 1) v2 += __shfl_down(v2, off, 64);
        if (threadIdx.x == 0) {
            const float sum_lse = v2 * LN2;   // sum_j lse_j
            // loss = -mean(lse) + 0.5*z_dim*(2*ls - 1) + log(n);  z_dim=2, n=8192
            out[0] = -sum_lse / (float)M_TOT + (2.0f * ls - 1.0f)
                     + 9.010913347279288f;
        }
    }
}

extern "C" void kernel_launch(void* const* d_in, const int* in_sizes, int n_in,
                              void* d_out, int out_size, void* d_ws, size_t ws_size,
                              hipStream_t stream)
{
    const float* z    = (const float*)d_in[0];
    const float* emb  = (const float*)d_in[1];
    const float* lsig = (const float*)d_in[2];
    const float* eps  = (const float*)d_in[3];
    const float* temp = (const float*)d_in[4];

    // ws layout: [0,64) counter (zeroed by k1), [64,320) bsum (64 floats,
    // fully overwritten before read), [512, 512+4MB) part.
    unsigned int* cnt = (unsigned int*)d_ws;
    float* bsum = (float*)d_ws + 16;               // byte offset 64
    float* part = (float*)d_ws + 128;              // byte offset 512

    dim3 grid1(NLCH, NICH);                        // 4 x 64 = 256 blocks (1/CU)
    gemm_partial_kernel<<<grid1, BLOCK, 0, stream>>>(z, emb, lsig, eps, temp,
                                                     part, cnt);
    reduce_final_kernel<<<M_TOT / BLOCK, BLOCK, 0, stream>>>(
        emb, lsig, eps, temp, part, bsum, cnt, (float*)d_out);
}